// Round 4
// baseline (2327.492 us; speedup 1.0000x reference)
//
#include <hip/hip_runtime.h>

typedef __attribute__((ext_vector_type(4))) float f32x4;
typedef __attribute__((ext_vector_type(8))) _Float16 f16x8;
typedef __attribute__((ext_vector_type(4))) _Float16 f16x4;
typedef unsigned short u16;
typedef unsigned int u32;

#define XGCAP 36864   // max non-reset rows we can store xg for (25 sigma margin)

__device__ __forceinline__ float sigm(float v){ return 1.0f / (1.0f + __expf(-v)); }
__device__ __forceinline__ float tanh_fast(float v){
  v = fminf(15.0f, fmaxf(-15.0f, v));
  float e = __expf(2.0f * v);
  return (e - 1.0f) / (e + 1.0f);
}
// async global->LDS DMA, 16B per lane; lds must be wave-uniform
__device__ __forceinline__ void gload16(const void* g, void* l){
  __builtin_amdgcn_global_load_lds((const __attribute__((address_space(1))) void*)g,
                                   (__attribute__((address_space(3))) void*)l, 16, 0, 0);
}

// ---------------------------------------------------------------------------
// P1: depth-ordered row lists (list0=reset, list1=t0/h0, list d+1=depth d).
// rows[] entry: t | b<<9 | flags<<16  (0=ys, 1=zero/reset, 2=h0). Pads tail.
// ---------------------------------------------------------------------------
__global__ void prep_lists(const void* __restrict__ resets_raw,
                           u32* __restrict__ rows, u32* __restrict__ off,
                           int* __restrict__ nlists)
{
  __shared__ u32 cnt[520];
  __shared__ u32 offs[521];
  __shared__ int is_bytes;
  const int tid = threadIdx.x;  // 128 threads, one per batch row
  for (int i = tid; i < 520; i += 128) cnt[i] = 0;
  if (tid == 0) is_bytes = 0;
  for (int i = tid; i < 64; i += 128) rows[65536 + i] = (2u << 16); // pad -> h0 path, no wait
  __syncthreads();
  { // dtype sniff: int32 resets -> every word 0/1; packed bytes -> words >1 whp
    const u32* w = (const u32*)resets_raw;
    int bad = 0;
    for (int i = tid; i < 4096; i += 128) bad |= (w[i] > 1u);
    if (bad) atomicOr(&is_bytes, 1);
  }
  __syncthreads();
  const bool as_bytes = (is_bytes != 0);
  const u32* ri32 = (const u32*)resets_raw;
  const unsigned char* ru8 = (const unsigned char*)resets_raw;
  const int b = tid;
  {
    int depth = 0;
    for (int t = 0; t < 512; ++t){
      bool rs = as_bytes ? (ru8[t*128 + b] != 0) : (ri32[t*128 + b] != 0u);
      depth = rs ? 0 : ((t == 0) ? 0 : depth + 1);
      int li = (depth == 0) ? (rs ? 0 : 1) : (depth + 1);
      atomicAdd(&cnt[li], 1u);
    }
  }
  __syncthreads();
  if (tid == 0){
    u32 s = 0; int mx = 0;
    for (int i = 0; i < 520; ++i){
      offs[i] = s; s += cnt[i];
      if (cnt[i]) mx = i;
    }
    offs[520] = s;
    *nlists = mx + 1;
  }
  __syncthreads();
  for (int i = tid; i < 521; i += 128) off[i] = offs[i];
  for (int i = tid; i < 520; i += 128) cnt[i] = 0;
  __syncthreads();
  {
    int depth = 0;
    for (int t = 0; t < 512; ++t){
      bool rs = as_bytes ? (ru8[t*128 + b] != 0) : (ri32[t*128 + b] != 0u);
      depth = rs ? 0 : ((t == 0) ? 0 : depth + 1);
      int li = (depth == 0) ? (rs ? 0 : 1) : (depth + 1);
      u32 p = offs[li] + atomicAdd(&cnt[li], 1u);
      u32 fl = rs ? 1u : ((t == 0) ? 2u : 0u);
      rows[p] = (u32)t | ((u32)b << 9) | (fl << 16);
    }
  }
}

// ---------------------------------------------------------------------------
// P2: pre-swizzled fp16 W LDS-images: wimg[jblk 0..7][kc 0..15][24576B].
// Image = 192 cols x 64 k fp16, col-row 128B, XOR-swizzled.
// Remapped col C = jblk*192 + cls*64 + jj  <-  source col cls*512 + jblk*64 + jj.
// ---------------------------------------------------------------------------
__global__ void prep_w(const float* __restrict__ Wi, const float* __restrict__ Wh,
                       char* __restrict__ wimg)
{
  __shared__ float tile[64][65];
  const int bc = blockIdx.x % 24;
  const int bk = blockIdx.x / 24;
  const int scol0 = (bc % 3) * 512 + (bc / 3) * 64;
  const int k0 = bk * 64;
  #pragma unroll
  for (int i = 0; i < 4; ++i){
    int idx = (int)threadIdx.x + i*256;
    int kk = idx >> 4, c4 = idx & 15;
    int k = k0 + kk;
    const float* src = (k < 512) ? (Wi + (size_t)k*1536 + scol0 + c4*4)
                                 : (Wh + (size_t)(k-512)*1536 + scol0 + c4*4);
    float4 v = *(const float4*)src;
    tile[kk][c4*4+0] = v.x; tile[kk][c4*4+1] = v.y;
    tile[kk][c4*4+2] = v.z; tile[kk][c4*4+3] = v.w;
  }
  __syncthreads();
  const int jb = bc / 3;
  #pragma unroll
  for (int i = 0; i < 4; ++i){
    int idx = (int)threadIdx.x + i*256;
    int cc = idx >> 4, k4 = idx & 15;
    int cimg = (bc % 3)*64 + cc;
    f16x4 c;
    c[0] = (_Float16)tile[k4*4+0][cc]; c[1] = (_Float16)tile[k4*4+1][cc];
    c[2] = (_Float16)tile[k4*4+2][cc]; c[3] = (_Float16)tile[k4*4+3][cc];
    int bby = k4*8;
    int sb = (bby & 8) | ((bby & 0x70) ^ ((cimg & 7) << 4));
    *(f16x4*)(wimg + ((size_t)(jb*16 + bk))*24576 + cimg*128 + sb) = c;
  }
}

// ---------------------------------------------------------------------------
// XG kernel: xg = x@Wi + bi for ALL rows (by list position), fp16 MFMA.
// Reset rows: full GRU elementwise epilogue -> ys + flag release (count 8).
// ---------------------------------------------------------------------------
__global__ __launch_bounds__(256, 2) void xg_gemm(
    const float* __restrict__ x, const float* __restrict__ bi,
    const float* __restrict__ bhn, const char* __restrict__ wimg,
    _Float16* __restrict__ xg, const u32* __restrict__ rows,
    const u32* __restrict__ off, u32* __restrict__ flags,
    float* __restrict__ out)
{
  __shared__ __align__(16) char smem[81920];  // A0 16K | A1 16K | W0 24K @32768 | W1 24K @57344
  const int tid = threadIdx.x;
  const int lane = tid & 63, wave = tid >> 6;
  const int tm = (int)blockIdx.x >> 3, jblk = (int)blockIdx.x & 7;
  float* ys = out + 65536;
  const u32 n0 = off[1];
  const size_t wbase = ((size_t)jblk*16)*24576;

  const float* rp[8];
  #pragma unroll
  for (int i = 0; i < 8; ++i){
    u32 e = rows[tm*128 + (tid>>4) + i*16];
    rp[i] = x + ((size_t)((e & 511u)*128u + ((e >> 9) & 127u)))*512 + (tid & 15)*4;
  }

  f32x4 acc[3][8];
  #pragma unroll
  for (int c = 0; c < 3; ++c)
    #pragma unroll
    for (int m = 0; m < 8; ++m) acc[c][m] = (f32x4){0.f,0.f,0.f,0.f};

  float4 areg[8];
  #pragma unroll
  for (int i = 0; i < 8; ++i) areg[i] = *(const float4*)(rp[i]);
  {
    const char* g = wimg + wbase + wave*6144 + lane*16;
    char* l = smem + 32768 + wave*6144;
    #pragma unroll
    for (int i = 0; i < 6; ++i) gload16(g + i*1024, l + i*1024);
  }
  #pragma unroll
  for (int i = 0; i < 8; ++i){
    int r = (tid>>4) + i*16, bby = (tid & 15)*8;
    int sb = (bby & 8) | ((bby & 0x70) ^ ((r & 7) << 4));
    f16x4 c; c[0]=(_Float16)areg[i].x; c[1]=(_Float16)areg[i].y;
             c[2]=(_Float16)areg[i].z; c[3]=(_Float16)areg[i].w;
    *(f16x4*)(smem + r*128 + sb) = c;
  }
  __syncthreads();

  for (int kc = 0; kc < 8; ++kc){
    const int cur = kc & 1;
    if (kc < 7){
      #pragma unroll
      for (int i = 0; i < 8; ++i) areg[i] = *(const float4*)(rp[i] + (kc+1)*64);
      const char* g = wimg + wbase + (size_t)(kc+1)*24576 + wave*6144 + lane*16;
      char* l = smem + 32768 + ((kc+1)&1)*24576 + wave*6144;
      #pragma unroll
      for (int i = 0; i < 6; ++i) gload16(g + i*1024, l + i*1024);
    }
    const char* Ab = smem + cur*16384;
    const char* Wb = smem + 32768 + cur*24576;
    #pragma unroll
    for (int kk = 0; kk < 2; ++kk){
      const int bby = kk*64 + (lane>>4)*16;
      f16x8 af[8];
      #pragma unroll
      for (int mi = 0; mi < 8; ++mi){
        int rr = mi*16 + (lane & 15);
        af[mi] = *(const f16x8*)(Ab + rr*128 + (bby ^ ((rr & 7) << 4)));
      }
      #pragma unroll
      for (int cls = 0; cls < 3; ++cls){
        int cc = cls*64 + wave*16 + (lane & 15);
        f16x8 wf = *(const f16x8*)(Wb + cc*128 + (bby ^ ((cc & 7) << 4)));
        #pragma unroll
        for (int mi = 0; mi < 8; ++mi)
          acc[cls][mi] = __builtin_amdgcn_mfma_f32_16x16x32_f16(af[mi], wf, acc[cls][mi], 0, 0, 0);
      }
    }
    if (kc < 7){
      char* An = smem + ((kc+1)&1)*16384;
      #pragma unroll
      for (int i = 0; i < 8; ++i){
        int r = (tid>>4) + i*16, bby = (tid & 15)*8;
        int sb = (bby & 8) | ((bby & 0x70) ^ ((r & 7) << 4));
        f16x4 c; c[0]=(_Float16)areg[i].x; c[1]=(_Float16)areg[i].y;
                 c[2]=(_Float16)areg[i].z; c[3]=(_Float16)areg[i].w;
        *(f16x4*)(An + r*128 + sb) = c;
      }
    }
    __syncthreads();
  }

  // epilogue: C/D layout col=lane&15, row=(lane>>4)*4+reg
  const int jloc = wave*16 + (lane & 15);
  const int j = jblk*64 + jloc;
  const float bir = bi[j], biz = bi[512 + j], bin = bi[1024 + j], bh = bhn[j];
  #pragma unroll
  for (int mi = 0; mi < 8; ++mi){
    #pragma unroll
    for (int rg = 0; rg < 4; ++rg){
      int r = mi*16 + (lane >> 4)*4 + rg;
      u32 e = rows[tm*128 + r];
      int tt = (int)(e & 511u), bb = (int)((e >> 9) & 127u);
      float xr = acc[0][mi][rg] + bir;
      float xz = acc[1][mi][rg] + biz;
      float xn = acc[2][mi][rg] + bin;
      if ((e >> 16) == 1u){        // reset row: h = (1-z)*n, hn = 0
        float rr = sigm(xr), zz = sigm(xz);
        float nn = tanh_fast(xn + rr*bh);
        ys[((size_t)(tt*128 + bb))*512 + j] = (1.f - zz)*nn;
      } else {
        u32 xi = (u32)(tm*128 + r) - n0;
        if (xi >= XGCAP) xi = 0;
        _Float16* p = xg + (size_t)xi*1536 + jblk*192 + jloc;
        p[0]   = (_Float16)xr;
        p[64]  = (_Float16)xz;
        p[128] = (_Float16)xn;
      }
    }
  }
  // release: flush stores, then bump per-row counters for reset rows
  __threadfence();
  __syncthreads();
  if (tid < 128){
    u32 e = rows[tm*128 + tid];
    if ((e >> 16) == 1u){
      u32 fidx = (e & 511u)*128u + ((e >> 9) & 127u);
      __hip_atomic_fetch_add(&flags[fidx], 1u, __ATOMIC_RELAXED, __HIP_MEMORY_SCOPE_AGENT);
    }
  }
}

// ---------------------------------------------------------------------------
// Scan: NO grid barriers. Tiles of all depth-lists enumerated in depth order,
// round-robined over co-resident blocks. Per-row readiness counters (==8 when
// all 8 column-slice tiles wrote the row). Consumers spin (relaxed loads +
// s_sleep) only for rows < mcount; overflow lanes produce discarded rows.
// ---------------------------------------------------------------------------
__global__ __launch_bounds__(256, 2) void gru_scan(
    const float* __restrict__ h0, const float* __restrict__ bhn,
    const char* __restrict__ wimg, const _Float16* __restrict__ xg,
    const u32* __restrict__ rows, const u32* __restrict__ off,
    const int* __restrict__ nlists, u32* __restrict__ flags,
    float* __restrict__ out)
{
  __shared__ __align__(16) char smem[65536];  // A0 8K | A1 8K | W0 24K @16384 | W1 24K @40960
  float* ys = out + 65536;
  const int L = *nlists;
  const u32 n0 = off[1];
  const int tid = threadIdx.x;
  const int lane = tid & 63, wave = tid >> 6;
  const int nblk = (int)gridDim.x;

  int myNext = (int)blockIdx.x;
  int gt = 0;
  for (int li = 1; li < L; ++li){
    const u32 offA = off[li];
    const int nA = (int)(off[li+1] - offA);
    const int tA = (nA + 63) >> 6;
    const int nt = tA * 8;
    while (myNext < gt + nt){
      const int tile = myNext - gt;
      myNext += nblk;
      const int tm = tile >> 3, jb = tile & 7;
      const u32 rowbase = offA + (u32)tm*64u;
      const int mcount = min(64, nA - tm*64);
      const size_t wbase = ((size_t)jb*16 + 8)*24576;

      // ---- wait for producers of our real rows (lane r<mcount, fl==0)
      {
        u32 e = rows[rowbase + lane];
        if (lane < mcount && (e >> 16) == 0u){
          u32 fidx = ((e & 511u) - 1u)*128u + ((e >> 9) & 127u);
          int guard = 0;
          while (__hip_atomic_load(&flags[fidx], __ATOMIC_RELAXED, __HIP_MEMORY_SCOPE_AGENT) < 8u){
            __builtin_amdgcn_s_sleep(2);
            if (++guard > (1 << 24)) break;
          }
        }
      }
      __threadfence();   // acquire: see producers' ys stores

      const float* rp[4];
      #pragma unroll
      for (int i = 0; i < 4; ++i){
        u32 e = rows[rowbase + (tid>>4) + i*16];
        int tt = (int)(e & 511u), bb = (int)((e >> 9) & 127u);
        const float* base = ((e >> 16) == 0u) ? (ys + ((size_t)((tt-1)*128 + bb))*512)
                                              : (h0 + (size_t)bb*512);
        rp[i] = base + (tid & 15)*4;
      }

      f32x4 acc[3][4];
      #pragma unroll
      for (int c = 0; c < 3; ++c)
        #pragma unroll
        for (int m = 0; m < 4; ++m) acc[c][m] = (f32x4){0.f,0.f,0.f,0.f};
      float hp[4][4];
      float4 areg[4];

      #pragma unroll
      for (int i = 0; i < 4; ++i) areg[i] = *(const float4*)(rp[i]);
      {
        const char* g = wimg + wbase + wave*6144 + lane*16;
        char* l = smem + 16384 + wave*6144;
        #pragma unroll
        for (int i = 0; i < 6; ++i) gload16(g + i*1024, l + i*1024);
      }
      #pragma unroll
      for (int i = 0; i < 4; ++i){
        int r = (tid>>4) + i*16, bby = (tid & 15)*8;
        int sb = (bby & 8) | ((bby & 0x70) ^ ((r & 7) << 4));
        f16x4 c; c[0]=(_Float16)areg[i].x; c[1]=(_Float16)areg[i].y;
                 c[2]=(_Float16)areg[i].z; c[3]=(_Float16)areg[i].w;
        *(f16x4*)(smem + r*128 + sb) = c;
      }
      __syncthreads();

      for (int kc = 0; kc < 8; ++kc){
        const int cur = kc & 1;
        if (kc < 7){
          #pragma unroll
          for (int i = 0; i < 4; ++i) areg[i] = *(const float4*)(rp[i] + (kc+1)*64);
          const char* g = wimg + wbase + (size_t)(kc+1)*24576 + wave*6144 + lane*16;
          char* l = smem + 16384 + ((kc+1)&1)*24576 + wave*6144;
          #pragma unroll
          for (int i = 0; i < 6; ++i) gload16(g + i*1024, l + i*1024);
        }
        const char* Ab = smem + cur*8192;
        const char* Wb = smem + 16384 + cur*24576;
        #pragma unroll
        for (int kk = 0; kk < 2; ++kk){
          const int bby = kk*64 + (lane>>4)*16;
          f16x8 af[4];
          #pragma unroll
          for (int mi = 0; mi < 4; ++mi){
            int rr = mi*16 + (lane & 15);
            af[mi] = *(const f16x8*)(Ab + rr*128 + (bby ^ ((rr & 7) << 4)));
          }
          #pragma unroll
          for (int cls = 0; cls < 3; ++cls){
            int cc = cls*64 + wave*16 + (lane & 15);
            f16x8 wf = *(const f16x8*)(Wb + cc*128 + (bby ^ ((cc & 7) << 4)));
            #pragma unroll
            for (int mi = 0; mi < 4; ++mi)
              acc[cls][mi] = __builtin_amdgcn_mfma_f32_16x16x32_f16(af[mi], wf, acc[cls][mi], 0, 0, 0);
          }
        }
        if (kc == jb){   // capture h_prev[j] from the A tile (j's chunk == jb)
          const int jloc = wave*16 + (lane & 15);
          const int bby = jloc*2;
          #pragma unroll
          for (int mi = 0; mi < 4; ++mi)
            #pragma unroll
            for (int rg = 0; rg < 4; ++rg){
              int r = mi*16 + (lane >> 4)*4 + rg;
              int sb = (bby & 0x0F) | ((bby & 0x70) ^ ((r & 7) << 4));
              hp[mi][rg] = (float)(*(const _Float16*)(Ab + r*128 + sb));
            }
        }
        if (kc < 7){
          char* An = smem + ((kc+1)&1)*8192;
          #pragma unroll
          for (int i = 0; i < 4; ++i){
            int r = (tid>>4) + i*16, bby = (tid & 15)*8;
            int sb = (bby & 8) | ((bby & 0x70) ^ ((r & 7) << 4));
            f16x4 c; c[0]=(_Float16)areg[i].x; c[1]=(_Float16)areg[i].y;
                     c[2]=(_Float16)areg[i].z; c[3]=(_Float16)areg[i].w;
            *(f16x4*)(An + r*128 + sb) = c;
          }
        }
        __syncthreads();
      }

      // epilogue: gates + h_new
      const int jloc = wave*16 + (lane & 15);
      const int j = jb*64 + jloc;
      const float bh = bhn[j];
      #pragma unroll
      for (int mi = 0; mi < 4; ++mi){
        #pragma unroll
        for (int rg = 0; rg < 4; ++rg){
          int r = mi*16 + (lane >> 4)*4 + rg;
          if (r < mcount){
            u32 lpos = rowbase + r;
            u32 e = rows[lpos];
            int tt = (int)(e & 511u), bb = (int)((e >> 9) & 127u);
            u32 xi = lpos - n0;
            if (xi >= XGCAP) xi = 0;
            const _Float16* p = xg + (size_t)xi*1536 + jb*192 + jloc;
            float rr = sigm((float)p[0]   + acc[0][mi][rg]);
            float zz = sigm((float)p[64]  + acc[1][mi][rg]);
            float nn = tanh_fast((float)p[128] + rr*(acc[2][mi][rg] + bh));
            ys[((size_t)(tt*128 + bb))*512 + j] = (1.f - zz)*nn + zz*hp[mi][rg];
          }
        }
      }
      // release: flush, then bump row counters
      __threadfence();
      __syncthreads();
      if (tid < 64 && tid < mcount){
        u32 e = rows[rowbase + tid];
        u32 fidx = (e & 511u)*128u + ((e >> 9) & 127u);
        __hip_atomic_fetch_add(&flags[fidx], 1u, __ATOMIC_RELAXED, __HIP_MEMORY_SCOPE_AGENT);
      }
    }
    gt += nt;
  }

  // h_final = ys[511] -> out[0:65536], gated on t=511 row readiness
  for (int v = (int)blockIdx.x; v < 512; v += nblk){
    const int b = v & 127, jq = v >> 7;
    if (tid == 0){
      int guard = 0;
      while (__hip_atomic_load(&flags[511*128 + b], __ATOMIC_RELAXED, __HIP_MEMORY_SCOPE_AGENT) < 8u){
        __builtin_amdgcn_s_sleep(2);
        if (++guard > (1 << 24)) break;
      }
    }
    __syncthreads();
    __threadfence();
    if (tid < 128)
      out[(size_t)b*512 + jq*128 + tid] = ys[((size_t)(511*128 + b))*512 + jq*128 + tid];
    __syncthreads();
  }
}

// ---------------------------------------------------------------------------
extern "C" void kernel_launch(void* const* d_in, const int* in_sizes, int n_in,
                              void* d_out, int out_size, void* d_ws, size_t ws_size,
                              hipStream_t stream)
{
  const float* x  = (const float*)d_in[0];
  const void*  resets = d_in[1];
  const float* h0 = (const float*)d_in[2];
  const float* Wi = (const float*)d_in[3];
  const float* bi = (const float*)d_in[4];
  const float* Wh = (const float*)d_in[5];
  const float* bhn= (const float*)d_in[6];
  float* out = (float*)d_out;

  char* ws = (char*)d_ws;
  u32* off    = (u32*)ws;                       // 521 u32
  int* nlists = (int*)(ws + 4096);
  u32* rows   = (u32*)(ws + 8192);              // 65536+64 u32
  u32* flags  = (u32*)(ws + 294912);            // 65536 u32 = 256 KB
  char* wimg  = ws + 589824;                    // 8*16*24576 = 3.07 MB
  _Float16* xg = (_Float16*)(ws + 4194304);     // XGCAP*1536 fp16 = 113 MB

  hipMemsetAsync(flags, 0, 65536*sizeof(u32), stream);   // re-zero every launch
  prep_lists<<<dim3(1), dim3(128), 0, stream>>>(resets, rows, off, nlists);
  prep_w<<<dim3(384), dim3(256), 0, stream>>>(Wi, Wh, wimg);
  xg_gemm<<<dim3(4096), dim3(256), 0, stream>>>(x, bi, bhn, wimg, xg, rows, off, flags, out);

  // co-residency guarantee for the spin-wait dataflow (no grid.sync inside)
  int perCU = 0;
  (void)hipOccupancyMaxActiveBlocksPerMultiprocessor(&perCU, gru_scan, 256, 0);
  if (perCU < 1) perCU = 1;
  int grid = perCU * 256;
  if (grid > 512) grid = 512;

  void* args[] = {(void*)&h0, (void*)&bhn, (void*)&wimg, (void*)&xg,
                  (void*)&rows, (void*)&off, (void*)&nlists, (void*)&flags, (void*)&out};
  hipLaunchCooperativeKernel(gru_scan, dim3(grid), dim3(256), args, 0, stream);

  (void)in_sizes; (void)n_in; (void)out_size; (void)ws_size;
}

// Round 5
// 1151.127 us; speedup vs baseline: 2.0219x; 2.0219x over previous
//
#include <hip/hip_runtime.h>

typedef __attribute__((ext_vector_type(4))) float f32x4;
typedef __attribute__((ext_vector_type(8))) _Float16 f16x8;
typedef __attribute__((ext_vector_type(4))) _Float16 f16x4;
typedef unsigned short u16;
typedef unsigned int u32;

#define XGCAP 36864   // max non-reset rows we can store xg for

__device__ __forceinline__ float sigm(float v){ return 1.0f / (1.0f + __expf(-v)); }
__device__ __forceinline__ float tanh_fast(float v){
  v = fminf(15.0f, fmaxf(-15.0f, v));
  float e = __expf(2.0f * v);
  return (e - 1.0f) / (e + 1.0f);
}
__device__ __forceinline__ void gload16(const void* g, void* l){
  __builtin_amdgcn_global_load_lds((const __attribute__((address_space(1))) void*)g,
                                   (__attribute__((address_space(3))) void*)l, 16, 0, 0);
}
// agent-scope (L2-bypassing, always-coherent) ops — no cache-nuking fences needed
__device__ __forceinline__ double aload(const double* p){
  return __hip_atomic_load(p, __ATOMIC_RELAXED, __HIP_MEMORY_SCOPE_AGENT);
}
__device__ __forceinline__ void astore(float* p, float v){
  __hip_atomic_store(p, v, __ATOMIC_RELAXED, __HIP_MEMORY_SCOPE_AGENT);
}
__device__ __forceinline__ float2 d2f2(double d){ union{double d; float2 f;} u; u.d = d; return u.f; }

// ---------------------------------------------------------------------------
// P1: depth-ordered row lists (list0=reset, list1=t0/h0, list d+1=depth d).
// rows[] entry: t | b<<9 | flags<<16  (0=ys, 1=zero/reset, 2=h0). Pads tail.
// ---------------------------------------------------------------------------
__global__ void prep_lists(const void* __restrict__ resets_raw,
                           u32* __restrict__ rows, u32* __restrict__ off,
                           int* __restrict__ nlists)
{
  __shared__ u32 cnt[520];
  __shared__ u32 offs[521];
  __shared__ int is_bytes;
  const int tid = threadIdx.x;  // 128 threads, one per batch row
  for (int i = tid; i < 520; i += 128) cnt[i] = 0;
  if (tid == 0) is_bytes = 0;
  for (int i = tid; i < 64; i += 128) rows[65536 + i] = (2u << 16); // pad -> h0 path, no wait
  __syncthreads();
  { // dtype sniff: int32 resets -> every word 0/1; packed bytes -> words >1 whp
    const u32* w = (const u32*)resets_raw;
    int bad = 0;
    for (int i = tid; i < 4096; i += 128) bad |= (w[i] > 1u);
    if (bad) atomicOr(&is_bytes, 1);
  }
  __syncthreads();
  const bool as_bytes = (is_bytes != 0);
  const u32* ri32 = (const u32*)resets_raw;
  const unsigned char* ru8 = (const unsigned char*)resets_raw;
  const int b = tid;
  {
    int depth = 0;
    for (int t = 0; t < 512; ++t){
      bool rs = as_bytes ? (ru8[t*128 + b] != 0) : (ri32[t*128 + b] != 0u);
      depth = rs ? 0 : ((t == 0) ? 0 : depth + 1);
      int li = (depth == 0) ? (rs ? 0 : 1) : (depth + 1);
      atomicAdd(&cnt[li], 1u);
    }
  }
  __syncthreads();
  if (tid == 0){
    u32 s = 0; int mx = 0;
    for (int i = 0; i < 520; ++i){
      offs[i] = s; s += cnt[i];
      if (cnt[i]) mx = i;
    }
    offs[520] = s;
    *nlists = mx + 1;
  }
  __syncthreads();
  for (int i = tid; i < 521; i += 128) off[i] = offs[i];
  for (int i = tid; i < 520; i += 128) cnt[i] = 0;
  __syncthreads();
  {
    int depth = 0;
    for (int t = 0; t < 512; ++t){
      bool rs = as_bytes ? (ru8[t*128 + b] != 0) : (ri32[t*128 + b] != 0u);
      depth = rs ? 0 : ((t == 0) ? 0 : depth + 1);
      int li = (depth == 0) ? (rs ? 0 : 1) : (depth + 1);
      u32 p = offs[li] + atomicAdd(&cnt[li], 1u);
      u32 fl = rs ? 1u : ((t == 0) ? 2u : 0u);
      rows[p] = (u32)t | ((u32)b << 9) | (fl << 16);
    }
  }
}

// ---------------------------------------------------------------------------
// P2: pre-swizzled fp16 W images: wimg[jblk 0..7][kc 0..15][24576B].
// Image = 192 cols x 64 k fp16, col-row 128B, XOR-swizzled.
// Remapped col C = jblk*192 + cls*64 + jj  <-  source col cls*512 + jblk*64 + jj.
// ---------------------------------------------------------------------------
__global__ void prep_w(const float* __restrict__ Wi, const float* __restrict__ Wh,
                       char* __restrict__ wimg)
{
  __shared__ float tile[64][65];
  const int bc = blockIdx.x % 24;
  const int bk = blockIdx.x / 24;
  const int scol0 = (bc % 3) * 512 + (bc / 3) * 64;
  const int k0 = bk * 64;
  #pragma unroll
  for (int i = 0; i < 4; ++i){
    int idx = (int)threadIdx.x + i*256;
    int kk = idx >> 4, c4 = idx & 15;
    int k = k0 + kk;
    const float* src = (k < 512) ? (Wi + (size_t)k*1536 + scol0 + c4*4)
                                 : (Wh + (size_t)(k-512)*1536 + scol0 + c4*4);
    float4 v = *(const float4*)src;
    tile[kk][c4*4+0] = v.x; tile[kk][c4*4+1] = v.y;
    tile[kk][c4*4+2] = v.z; tile[kk][c4*4+3] = v.w;
  }
  __syncthreads();
  const int jb = bc / 3;
  #pragma unroll
  for (int i = 0; i < 4; ++i){
    int idx = (int)threadIdx.x + i*256;
    int cc = idx >> 4, k4 = idx & 15;
    int cimg = (bc % 3)*64 + cc;
    f16x4 c;
    c[0] = (_Float16)tile[k4*4+0][cc]; c[1] = (_Float16)tile[k4*4+1][cc];
    c[2] = (_Float16)tile[k4*4+2][cc]; c[3] = (_Float16)tile[k4*4+3][cc];
    int bby = k4*8;
    int sb = (bby & 8) | ((bby & 0x70) ^ ((cimg & 7) << 4));
    *(f16x4*)(wimg + ((size_t)(jb*16 + bk))*24576 + cimg*128 + sb) = c;
  }
}

// ---------------------------------------------------------------------------
// XG kernel: xg = x@Wi + bi for ALL rows (by list position), fp16 MFMA.
// Reset rows: full GRU elementwise epilogue -> ys + flag bump (no fence —
// scan launches after; kernel boundary provides visibility).
// ---------------------------------------------------------------------------
__global__ __launch_bounds__(256, 2) void xg_gemm(
    const float* __restrict__ x, const float* __restrict__ bi,
    const float* __restrict__ bhn, const char* __restrict__ wimg,
    _Float16* __restrict__ xg, const u32* __restrict__ rows,
    const u32* __restrict__ off, u32* __restrict__ flags,
    float* __restrict__ out)
{
  __shared__ __align__(16) char smem[81920];  // A0 16K | A1 16K | W0 24K @32768 | W1 24K @57344
  const int tid = threadIdx.x;
  const int lane = tid & 63, wave = tid >> 6;
  const int tm = (int)blockIdx.x >> 3, jblk = (int)blockIdx.x & 7;
  float* ys = out + 65536;
  const u32 n0 = off[1];
  const size_t wbase = ((size_t)jblk*16)*24576;

  const float* rp[8];
  #pragma unroll
  for (int i = 0; i < 8; ++i){
    u32 e = rows[tm*128 + (tid>>4) + i*16];
    rp[i] = x + ((size_t)((e & 511u)*128u + ((e >> 9) & 127u)))*512 + (tid & 15)*4;
  }

  f32x4 acc[3][8];
  #pragma unroll
  for (int c = 0; c < 3; ++c)
    #pragma unroll
    for (int m = 0; m < 8; ++m) acc[c][m] = (f32x4){0.f,0.f,0.f,0.f};

  float4 areg[8];
  #pragma unroll
  for (int i = 0; i < 8; ++i) areg[i] = *(const float4*)(rp[i]);
  {
    const char* g = wimg + wbase + wave*6144 + lane*16;
    char* l = smem + 32768 + wave*6144;
    #pragma unroll
    for (int i = 0; i < 6; ++i) gload16(g + i*1024, l + i*1024);
  }
  #pragma unroll
  for (int i = 0; i < 8; ++i){
    int r = (tid>>4) + i*16, bby = (tid & 15)*8;
    int sb = (bby & 8) | ((bby & 0x70) ^ ((r & 7) << 4));
    f16x4 c; c[0]=(_Float16)areg[i].x; c[1]=(_Float16)areg[i].y;
             c[2]=(_Float16)areg[i].z; c[3]=(_Float16)areg[i].w;
    *(f16x4*)(smem + r*128 + sb) = c;
  }
  __syncthreads();

  for (int kc = 0; kc < 8; ++kc){
    const int cur = kc & 1;
    if (kc < 7){
      #pragma unroll
      for (int i = 0; i < 8; ++i) areg[i] = *(const float4*)(rp[i] + (kc+1)*64);
      const char* g = wimg + wbase + (size_t)(kc+1)*24576 + wave*6144 + lane*16;
      char* l = smem + 32768 + ((kc+1)&1)*24576 + wave*6144;
      #pragma unroll
      for (int i = 0; i < 6; ++i) gload16(g + i*1024, l + i*1024);
    }
    const char* Ab = smem + cur*16384;
    const char* Wb = smem + 32768 + cur*24576;
    #pragma unroll
    for (int kk = 0; kk < 2; ++kk){
      const int bby = kk*64 + (lane>>4)*16;
      f16x8 af[8];
      #pragma unroll
      for (int mi = 0; mi < 8; ++mi){
        int rr = mi*16 + (lane & 15);
        af[mi] = *(const f16x8*)(Ab + rr*128 + (bby ^ ((rr & 7) << 4)));
      }
      #pragma unroll
      for (int cls = 0; cls < 3; ++cls){
        int cc = cls*64 + wave*16 + (lane & 15);
        f16x8 wf = *(const f16x8*)(Wb + cc*128 + (bby ^ ((cc & 7) << 4)));
        #pragma unroll
        for (int mi = 0; mi < 8; ++mi)
          acc[cls][mi] = __builtin_amdgcn_mfma_f32_16x16x32_f16(af[mi], wf, acc[cls][mi], 0, 0, 0);
      }
    }
    if (kc < 7){
      char* An = smem + ((kc+1)&1)*16384;
      #pragma unroll
      for (int i = 0; i < 8; ++i){
        int r = (tid>>4) + i*16, bby = (tid & 15)*8;
        int sb = (bby & 8) | ((bby & 0x70) ^ ((r & 7) << 4));
        f16x4 c; c[0]=(_Float16)areg[i].x; c[1]=(_Float16)areg[i].y;
                 c[2]=(_Float16)areg[i].z; c[3]=(_Float16)areg[i].w;
        *(f16x4*)(An + r*128 + sb) = c;
      }
    }
    __syncthreads();
  }

  // epilogue: C/D layout col=lane&15, row=(lane>>4)*4+reg
  const int jloc = wave*16 + (lane & 15);
  const int j = jblk*64 + jloc;
  const float bir = bi[j], biz = bi[512 + j], bin = bi[1024 + j], bh = bhn[j];
  #pragma unroll
  for (int mi = 0; mi < 8; ++mi){
    #pragma unroll
    for (int rg = 0; rg < 4; ++rg){
      int r = mi*16 + (lane >> 4)*4 + rg;
      u32 e = rows[tm*128 + r];
      int tt = (int)(e & 511u), bb = (int)((e >> 9) & 127u);
      float xr = acc[0][mi][rg] + bir;
      float xz = acc[1][mi][rg] + biz;
      float xn = acc[2][mi][rg] + bin;
      if ((e >> 16) == 1u){        // reset row: h = (1-z)*n, hn = 0
        float rr = sigm(xr), zz = sigm(xz);
        float nn = tanh_fast(xn + rr*bh);
        ys[((size_t)(tt*128 + bb))*512 + j] = (1.f - zz)*nn;
      } else {
        u32 xi = (u32)(tm*128 + r) - n0;
        if (xi >= XGCAP) xi = 0;
        _Float16* p = xg + (size_t)xi*1536 + jblk*192 + jloc;
        p[0]   = (_Float16)xr;
        p[64]  = (_Float16)xz;
        p[128] = (_Float16)xn;
      }
    }
  }
  __syncthreads();   // all stores drained (vmcnt0 at barrier) before flag bumps
  if (tid < 128){
    u32 e = rows[tm*128 + tid];
    if ((e >> 16) == 1u){
      u32 fidx = (e & 511u)*128u + ((e >> 9) & 127u);
      __hip_atomic_fetch_add(&flags[fidx], 1u, __ATOMIC_RELAXED, __HIP_MEMORY_SCOPE_AGENT);
    }
  }
}

// ---------------------------------------------------------------------------
// Scan: dataflow, NO fences. ys communicated via agent-scope (L2-bypassing)
// atomic loads/stores; flags via agent atomics. W fragments read directly
// from global (stays L2-resident). A gathered with register prefetch depth 3
// into a 4-buffer LDS ring — collapses the serial chunk-latency chain.
// ---------------------------------------------------------------------------
__global__ __launch_bounds__(256, 2) void gru_scan(
    const float* __restrict__ h0, const float* __restrict__ bhn,
    const char* __restrict__ wimg, const _Float16* __restrict__ xg,
    const u32* __restrict__ rows, const u32* __restrict__ off,
    const int* __restrict__ nlists, u32* __restrict__ flags,
    float* __restrict__ out)
{
  __shared__ __align__(16) char smem[32768];  // ring of 4 x 8 KB A-chunk buffers
  float* ys = out + 65536;
  const int L = *nlists;
  const u32 n0 = off[1];
  const int tid = threadIdx.x;
  const int lane = tid & 63, wave = tid >> 6;
  const int nblk = (int)gridDim.x;

  int myNext = (int)blockIdx.x;
  int gt = 0;
  for (int li = 1; li < L; ++li){
    const u32 offA = off[li];
    const int nA = (int)(off[li+1] - offA);
    const int tA = (nA + 63) >> 6;
    const int nt = tA * 8;
    while (myNext < gt + nt){
      const int tile = myNext - gt;
      myNext += nblk;
      const int tm = tile >> 3, jb = tile & 7;
      const u32 rowbase = offA + (u32)tm*64u;
      const int mcount = min(64, nA - tm*64);
      const char* wp = wimg + ((size_t)jb*16 + 8)*24576;

      // ---- wait: wave 0 polls per-row flags; barrier releases the block
      if (wave == 0){
        u32 e = rows[rowbase + lane];
        if (lane < mcount && (e >> 16) == 0u){
          u32 fidx = ((e & 511u) - 1u)*128u + ((e >> 9) & 127u);
          int guard = 0;
          while (__hip_atomic_load(&flags[fidx], __ATOMIC_RELAXED, __HIP_MEMORY_SCOPE_AGENT) < 8u){
            __builtin_amdgcn_s_sleep(1);
            if (++guard > (1 << 20)) break;
          }
        }
      }
      __syncthreads();

      const float* rp[4];
      #pragma unroll
      for (int i = 0; i < 4; ++i){
        u32 e = rows[rowbase + (tid>>4) + i*16];
        int tt = (int)(e & 511u), bb = (int)((e >> 9) & 127u);
        const float* base = ((e >> 16) == 0u) ? (ys + ((size_t)((tt-1)*128 + bb))*512)
                                              : (h0 + (size_t)bb*512);
        rp[i] = base + (tid & 15)*4;
      }

      f32x4 acc[3][4];
      #pragma unroll
      for (int c = 0; c < 3; ++c)
        #pragma unroll
        for (int m = 0; m < 4; ++m) acc[c][m] = (f32x4){0.f,0.f,0.f,0.f};
      float hp[4][4];
      double s0[4][2], s1[4][2], s2[4][2];

#define ALOAD(S, CK) do{ \
    _Pragma("unroll") for (int i_ = 0; i_ < 4; ++i_){ \
      const double* p_ = (const double*)(rp[i_] + (CK)*64); \
      S[i_][0] = aload(p_); S[i_][1] = aload(p_ + 1); } }while(0)

#define AWRITE(S, CK) do{ \
    char* An_ = smem + ((CK) & 3)*8192; \
    _Pragma("unroll") for (int i_ = 0; i_ < 4; ++i_){ \
      float2 u0_ = d2f2(S[i_][0]), u1_ = d2f2(S[i_][1]); \
      int r_ = (tid>>4) + i_*16, bby_ = (tid & 15)*8; \
      int sb_ = (bby_ & 8) | ((bby_ & 0x70) ^ ((r_ & 7) << 4)); \
      f16x4 c_; c_[0]=(_Float16)u0_.x; c_[1]=(_Float16)u0_.y; \
                c_[2]=(_Float16)u1_.x; c_[3]=(_Float16)u1_.y; \
      *(f16x4*)(An_ + r_*128 + sb_) = c_; } }while(0)

#define COMPUTE(KC) do{ \
    const char* Ab_ = smem + ((KC) & 3)*8192; \
    _Pragma("unroll") for (int kk_ = 0; kk_ < 2; ++kk_){ \
      const int bby_ = kk_*64 + (lane>>4)*16; \
      f16x8 af_[4]; \
      _Pragma("unroll") for (int mi_ = 0; mi_ < 4; ++mi_){ \
        int rr_ = mi_*16 + (lane & 15); \
        af_[mi_] = *(const f16x8*)(Ab_ + rr_*128 + (bby_ ^ ((rr_ & 7) << 4))); } \
      _Pragma("unroll") for (int cl_ = 0; cl_ < 3; ++cl_){ \
        int cc_ = cl_*64 + wave*16 + (lane & 15); \
        f16x8 wf_ = *(const f16x8*)(wp + (size_t)(KC)*24576 + cc_*128 + (bby_ ^ ((cc_ & 7) << 4))); \
        _Pragma("unroll") for (int mi_ = 0; mi_ < 4; ++mi_) \
          acc[cl_][mi_] = __builtin_amdgcn_mfma_f32_16x16x32_f16(af_[mi_], wf_, acc[cl_][mi_], 0, 0, 0); } } \
    if ((KC) == jb){ \
      const int jl_ = wave*16 + (lane & 15); \
      const int bb2_ = jl_*2; \
      _Pragma("unroll") for (int mi_ = 0; mi_ < 4; ++mi_) \
        _Pragma("unroll") for (int rg_ = 0; rg_ < 4; ++rg_){ \
          int r2_ = mi_*16 + (lane >> 4)*4 + rg_; \
          int sb2_ = (bb2_ & 0x0F) | ((bb2_ & 0x70) ^ ((r2_ & 7) << 4)); \
          hp[mi_][rg_] = (float)(*(const _Float16*)(Ab_ + r2_*128 + sb2_)); } } }while(0)

      // prologue: 3 chunk-loads in flight, write chunk 0
      ALOAD(s0, 0); ALOAD(s1, 1); ALOAD(s2, 2);
      AWRITE(s0, 0);
      __syncthreads();
      // steady: load k+3 | compute k | write k+1 | barrier
      ALOAD(s0, 3); COMPUTE(0); AWRITE(s1, 1); __syncthreads();
      ALOAD(s1, 4); COMPUTE(1); AWRITE(s2, 2); __syncthreads();
      ALOAD(s2, 5); COMPUTE(2); AWRITE(s0, 3); __syncthreads();
      ALOAD(s0, 6); COMPUTE(3); AWRITE(s1, 4); __syncthreads();
      ALOAD(s1, 7); COMPUTE(4); AWRITE(s2, 5); __syncthreads();
                    COMPUTE(5); AWRITE(s0, 6); __syncthreads();
                    COMPUTE(6); AWRITE(s1, 7); __syncthreads();
                    COMPUTE(7);
#undef ALOAD
#undef AWRITE
#undef COMPUTE

      // epilogue: gates + h_new (agent-scope stores -> visible to consumers)
      const int jloc = wave*16 + (lane & 15);
      const int j = jb*64 + jloc;
      const float bh = bhn[j];
      #pragma unroll
      for (int mi = 0; mi < 4; ++mi){
        #pragma unroll
        for (int rg = 0; rg < 4; ++rg){
          int r = mi*16 + (lane >> 4)*4 + rg;
          if (r < mcount){
            u32 lpos = rowbase + r;
            u32 e = rows[lpos];
            int tt = (int)(e & 511u), bb = (int)((e >> 9) & 127u);
            u32 xi = lpos - n0;
            if (xi >= XGCAP) xi = 0;
            const _Float16* p = xg + (size_t)xi*1536 + jb*192 + jloc;
            float rr = sigm((float)p[0]   + acc[0][mi][rg]);
            float zz = sigm((float)p[64]  + acc[1][mi][rg]);
            float nn = tanh_fast((float)p[128] + rr*(acc[2][mi][rg] + bh));
            astore(&ys[((size_t)(tt*128 + bb))*512 + j], (1.f - zz)*nn + zz*hp[mi][rg]);
          }
        }
      }
      __syncthreads();   // vmcnt(0) drained -> stores at coherence point
      if (tid < mcount){
        u32 e = rows[rowbase + tid];
        u32 fidx = (e & 511u)*128u + ((e >> 9) & 127u);
        __hip_atomic_fetch_add(&flags[fidx], 1u, __ATOMIC_RELAXED, __HIP_MEMORY_SCOPE_AGENT);
      }
    }
    gt += nt;
  }

  // h_final = ys[511] -> out[0:65536], gated on t=511 row readiness
  for (int v = (int)blockIdx.x; v < 512; v += nblk){
    const int b = v & 127, jq = v >> 7;
    if (tid == 0){
      int guard = 0;
      while (__hip_atomic_load(&flags[511*128 + b], __ATOMIC_RELAXED, __HIP_MEMORY_SCOPE_AGENT) < 8u){
        __builtin_amdgcn_s_sleep(1);
        if (++guard > (1 << 20)) break;
      }
    }
    __syncthreads();
    if (tid < 128){
      const float* src = &ys[((size_t)(511*128 + b))*512 + jq*128 + tid];
      float val;
      { // 4-byte agent-scope load (fresh)
        val = __hip_atomic_load(src, __ATOMIC_RELAXED, __HIP_MEMORY_SCOPE_AGENT);
      }
      out[(size_t)b*512 + jq*128 + tid] = val;
    }
    __syncthreads();
  }
}

// ---------------------------------------------------------------------------
extern "C" void kernel_launch(void* const* d_in, const int* in_sizes, int n_in,
                              void* d_out, int out_size, void* d_ws, size_t ws_size,
                              hipStream_t stream)
{
  const float* x  = (const float*)d_in[0];
  const void*  resets = d_in[1];
  const float* h0 = (const float*)d_in[2];
  const float* Wi = (const float*)d_in[3];
  const float* bi = (const float*)d_in[4];
  const float* Wh = (const float*)d_in[5];
  const float* bhn= (const float*)d_in[6];
  float* out = (float*)d_out;

  char* ws = (char*)d_ws;
  u32* off    = (u32*)ws;                       // 521 u32
  int* nlists = (int*)(ws + 4096);
  u32* rows   = (u32*)(ws + 8192);              // 65536+64 u32
  u32* flags  = (u32*)(ws + 294912);            // 65536 u32
  char* wimg  = ws + 589824;                    // 8*16*24576 = 3.07 MB
  _Float16* xg = (_Float16*)(ws + 4194304);     // XGCAP*1536 fp16 = 113 MB

  hipMemsetAsync(flags, 0, 65536*sizeof(u32), stream);
  prep_lists<<<dim3(1), dim3(128), 0, stream>>>(resets, rows, off, nlists);
  prep_w<<<dim3(384), dim3(256), 0, stream>>>(Wi, Wh, wimg);
  xg_gemm<<<dim3(4096), dim3(256), 0, stream>>>(x, bi, bhn, wimg, xg, rows, off, flags, out);

  // co-residency guarantee for the spin-wait dataflow
  int perCU = 0;
  (void)hipOccupancyMaxActiveBlocksPerMultiprocessor(&perCU, gru_scan, 256, 0);
  if (perCU < 1) perCU = 1;
  int grid = perCU * 256;
  if (grid > 1024) grid = 1024;

  void* args[] = {(void*)&h0, (void*)&bhn, (void*)&wimg, (void*)&xg,
                  (void*)&rows, (void*)&off, (void*)&nlists, (void*)&flags, (void*)&out};
  hipLaunchCooperativeKernel(gru_scan, dim3(grid), dim3(256), args, 0, stream);

  (void)in_sizes; (void)n_in; (void)out_size; (void)ws_size;
}

// Round 6
// 921.409 us; speedup vs baseline: 2.5260x; 1.2493x over previous
//
#include <hip/hip_runtime.h>

typedef __attribute__((ext_vector_type(4))) float f32x4;
typedef __attribute__((ext_vector_type(8))) _Float16 f16x8;
typedef __attribute__((ext_vector_type(4))) _Float16 f16x4;
typedef unsigned short u16;
typedef unsigned int u32;
typedef unsigned long long u64;

#define XGCAP 36864   // max non-reset rows we can store xg for

__device__ __forceinline__ float sigm(float v){ return 1.0f / (1.0f + __expf(-v)); }
__device__ __forceinline__ float tanh_fast(float v){
  v = fminf(15.0f, fmaxf(-15.0f, v));
  float e = __expf(2.0f * v);
  return (e - 1.0f) / (e + 1.0f);
}
__device__ __forceinline__ void gload16(const void* g, void* l){
  __builtin_amdgcn_global_load_lds((const __attribute__((address_space(1))) void*)g,
                                   (__attribute__((address_space(3))) void*)l, 16, 0, 0);
}
// agent-scope (L2-bypassing, always-coherent) ops — no cache-nuking fences needed
__device__ __forceinline__ double aload(const double* p){
  return __hip_atomic_load(p, __ATOMIC_RELAXED, __HIP_MEMORY_SCOPE_AGENT);
}
__device__ __forceinline__ void astore(float* p, float v){
  __hip_atomic_store(p, v, __ATOMIC_RELAXED, __HIP_MEMORY_SCOPE_AGENT);
}
__device__ __forceinline__ float2 d2f2(double d){ union{double d; float2 f;} u; u.d = d; return u.f; }

// ---------------------------------------------------------------------------
// P1: depth-ordered row lists. ONE block, 512 threads. resets staged into an
// 8 KB LDS bitmap first (coalesced ballot-pack), so the two serial t-loops
// (count, place) run at LDS latency instead of L2 latency.
// list0=reset, list1=t0/h0, list d+1=depth d.
// rows[] entry: t | b<<9 | fl<<16  (0=ys, 1=zero/reset, 2=h0). Pads tail.
// ---------------------------------------------------------------------------
__global__ __launch_bounds__(512) void prep_lists(
    const void* __restrict__ resets_raw,
    u32* __restrict__ rows, u32* __restrict__ off, int* __restrict__ nlists)
{
  __shared__ u32 bitmap[2048];   // 65536 bits, bit index = t*128+b
  __shared__ u32 cnt[520];
  __shared__ u32 offs[521];
  __shared__ u32 cur[520];
  __shared__ int is_bytes;
  const int tid = threadIdx.x;
  const int lane = tid & 63, wave = tid >> 6;
  for (int i = tid; i < 2048; i += 512) bitmap[i] = 0;
  for (int i = tid; i < 520; i += 512){ cnt[i] = 0; cur[i] = 0; }
  if (tid == 0) is_bytes = 0;
  for (int i = tid; i < 64; i += 512) rows[65536 + i] = (2u << 16); // pad -> h0 path
  __syncthreads();
  { // dtype sniff: int32 resets -> every word 0/1; packed bytes -> words >1 whp
    const u32* w = (const u32*)resets_raw;
    int bad = 0;
    for (int i = tid; i < 4096; i += 512) bad |= (w[i] > 1u);
    if (bad) atomicOr(&is_bytes, 1);
  }
  __syncthreads();
  if (is_bytes){
    // bytes: 65536 bytes = 16384 u32 words; word i -> bits 4i..4i+3
    const u32* wb = (const u32*)resets_raw;
    for (int i = tid; i < 16384; i += 512){
      u32 v = wb[i];
      u32 bits = ((v & 0xFFu) ? 1u : 0u) | (((v >> 8) & 0xFFu) ? 2u : 0u)
               | (((v >> 16) & 0xFFu) ? 4u : 0u) | (((v >> 24) & 0xFFu) ? 8u : 0u);
      if (bits) atomicOr(&bitmap[i >> 3], bits << ((i & 7) * 4));
    }
  } else {
    // int32: 65536 words; coalesced read + wave ballot -> 64 bits per wave/round
    const u32* w = (const u32*)resets_raw;
    for (int r = 0; r < 128; ++r){
      u32 v = w[r * 512 + tid];
      u64 m = __ballot(v != 0u);
      if (lane == 0){
        int idx = r * 16 + wave * 2;
        bitmap[idx]     = (u32)m;
        bitmap[idx + 1] = (u32)(m >> 32);
      }
    }
  }
  __syncthreads();
  // pass1: count (threads 0..127 = batch b, serial over t at LDS speed)
  if (tid < 128){
    const int b = tid;
    int depth = 0;
    for (int t = 0; t < 512; ++t){
      int pos = t * 128 + b;
      bool rs = (bitmap[pos >> 5] >> (pos & 31)) & 1u;
      depth = rs ? 0 : ((t == 0) ? 0 : depth + 1);
      int li = (depth == 0) ? (rs ? 0 : 1) : (depth + 1);
      atomicAdd(&cnt[li], 1u);
    }
  }
  __syncthreads();
  if (tid == 0){
    u32 s = 0; int mx = 0;
    for (int i = 0; i < 520; ++i){
      offs[i] = s; s += cnt[i];
      if (cnt[i]) mx = i;
    }
    offs[520] = s;
    *nlists = mx + 1;
  }
  __syncthreads();
  for (int i = tid; i < 521; i += 512) off[i] = offs[i];
  __syncthreads();
  // pass2: place
  if (tid < 128){
    const int b = tid;
    int depth = 0;
    for (int t = 0; t < 512; ++t){
      int pos = t * 128 + b;
      bool rs = (bitmap[pos >> 5] >> (pos & 31)) & 1u;
      depth = rs ? 0 : ((t == 0) ? 0 : depth + 1);
      int li = (depth == 0) ? (rs ? 0 : 1) : (depth + 1);
      u32 p = offs[li] + atomicAdd(&cur[li], 1u);
      u32 fl = rs ? 1u : ((t == 0) ? 2u : 0u);
      rows[p] = (u32)t | ((u32)b << 9) | (fl << 16);
    }
  }
}

// ---------------------------------------------------------------------------
// P2: pre-swizzled fp16 W images: wimg[jblk 0..7][kc 0..15][24576B].
// Image = 192 cols x 64 k fp16, col-row 128B, XOR-swizzled.
// Remapped col C = jblk*192 + cls*64 + jj  <-  source col cls*512 + jblk*64 + jj.
// ---------------------------------------------------------------------------
__global__ void prep_w(const float* __restrict__ Wi, const float* __restrict__ Wh,
                       char* __restrict__ wimg)
{
  __shared__ float tile[64][65];
  const int bc = blockIdx.x % 24;
  const int bk = blockIdx.x / 24;
  const int scol0 = (bc % 3) * 512 + (bc / 3) * 64;
  const int k0 = bk * 64;
  #pragma unroll
  for (int i = 0; i < 4; ++i){
    int idx = (int)threadIdx.x + i*256;
    int kk = idx >> 4, c4 = idx & 15;
    int k = k0 + kk;
    const float* src = (k < 512) ? (Wi + (size_t)k*1536 + scol0 + c4*4)
                                 : (Wh + (size_t)(k-512)*1536 + scol0 + c4*4);
    float4 v = *(const float4*)src;
    tile[kk][c4*4+0] = v.x; tile[kk][c4*4+1] = v.y;
    tile[kk][c4*4+2] = v.z; tile[kk][c4*4+3] = v.w;
  }
  __syncthreads();
  const int jb = bc / 3;
  #pragma unroll
  for (int i = 0; i < 4; ++i){
    int idx = (int)threadIdx.x + i*256;
    int cc = idx >> 4, k4 = idx & 15;
    int cimg = (bc % 3)*64 + cc;
    f16x4 c;
    c[0] = (_Float16)tile[k4*4+0][cc]; c[1] = (_Float16)tile[k4*4+1][cc];
    c[2] = (_Float16)tile[k4*4+2][cc]; c[3] = (_Float16)tile[k4*4+3][cc];
    int bby = k4*8;
    int sb = (bby & 8) | ((bby & 0x70) ^ ((cimg & 7) << 4));
    *(f16x4*)(wimg + ((size_t)(jb*16 + bk))*24576 + cimg*128 + sb) = c;
  }
}

// ---------------------------------------------------------------------------
// XG kernel: xg = x@Wi + bi for ALL rows (by list position), fp16 MFMA.
// Block remap groups all 8 jblk-blocks of one M-tile on the SAME XCD
// (bid%8 -> XCD round-robin heuristic), so the gathered 256 KB x-tile is
// fetched once and shared via that XCD's L2 (kills the 8x x re-read).
// Reset rows: full GRU elementwise epilogue -> ys + flag bump.
// ---------------------------------------------------------------------------
__global__ __launch_bounds__(256, 2) void xg_gemm(
    const float* __restrict__ x, const float* __restrict__ bi,
    const float* __restrict__ bhn, const char* __restrict__ wimg,
    _Float16* __restrict__ xg, const u32* __restrict__ rows,
    const u32* __restrict__ off, u32* __restrict__ flags,
    float* __restrict__ out)
{
  __shared__ __align__(16) char smem[81920];  // A0 16K | A1 16K | W0 24K @32768 | W1 24K @57344
  const int tid = threadIdx.x;
  const int lane = tid & 63, wave = tid >> 6;
  // bid = m%8 + 8*jb + 64*(m/8)  ->  all 8 jb of m share bid%8 (same XCD), concurrent
  const int c_  = (int)blockIdx.x & 7;
  const int q_  = (int)blockIdx.x >> 3;
  const int jblk = q_ & 7;
  const int tm = c_ + ((q_ >> 3) << 3);
  float* ys = out + 65536;
  const u32 n0 = off[1];
  const size_t wbase = ((size_t)jblk*16)*24576;

  const float* rp[8];
  #pragma unroll
  for (int i = 0; i < 8; ++i){
    u32 e = rows[tm*128 + (tid>>4) + i*16];
    rp[i] = x + ((size_t)((e & 511u)*128u + ((e >> 9) & 127u)))*512 + (tid & 15)*4;
  }

  f32x4 acc[3][8];
  #pragma unroll
  for (int c = 0; c < 3; ++c)
    #pragma unroll
    for (int m = 0; m < 8; ++m) acc[c][m] = (f32x4){0.f,0.f,0.f,0.f};

  float4 areg[8];
  #pragma unroll
  for (int i = 0; i < 8; ++i) areg[i] = *(const float4*)(rp[i]);
  {
    const char* g = wimg + wbase + wave*6144 + lane*16;
    char* l = smem + 32768 + wave*6144;
    #pragma unroll
    for (int i = 0; i < 6; ++i) gload16(g + i*1024, l + i*1024);
  }
  #pragma unroll
  for (int i = 0; i < 8; ++i){
    int r = (tid>>4) + i*16, bby = (tid & 15)*8;
    int sb = (bby & 8) | ((bby & 0x70) ^ ((r & 7) << 4));
    f16x4 c; c[0]=(_Float16)areg[i].x; c[1]=(_Float16)areg[i].y;
             c[2]=(_Float16)areg[i].z; c[3]=(_Float16)areg[i].w;
    *(f16x4*)(smem + r*128 + sb) = c;
  }
  __syncthreads();

  for (int kc = 0; kc < 8; ++kc){
    const int cur = kc & 1;
    if (kc < 7){
      #pragma unroll
      for (int i = 0; i < 8; ++i) areg[i] = *(const float4*)(rp[i] + (kc+1)*64);
      const char* g = wimg + wbase + (size_t)(kc+1)*24576 + wave*6144 + lane*16;
      char* l = smem + 32768 + ((kc+1)&1)*24576 + wave*6144;
      #pragma unroll
      for (int i = 0; i < 6; ++i) gload16(g + i*1024, l + i*1024);
    }
    const char* Ab = smem + cur*16384;
    const char* Wb = smem + 32768 + cur*24576;
    #pragma unroll
    for (int kk = 0; kk < 2; ++kk){
      const int bby = kk*64 + (lane>>4)*16;
      f16x8 af[8];
      #pragma unroll
      for (int mi = 0; mi < 8; ++mi){
        int rr = mi*16 + (lane & 15);
        af[mi] = *(const f16x8*)(Ab + rr*128 + (bby ^ ((rr & 7) << 4)));
      }
      #pragma unroll
      for (int cls = 0; cls < 3; ++cls){
        int cc = cls*64 + wave*16 + (lane & 15);
        f16x8 wf = *(const f16x8*)(Wb + cc*128 + (bby ^ ((cc & 7) << 4)));
        #pragma unroll
        for (int mi = 0; mi < 8; ++mi)
          acc[cls][mi] = __builtin_amdgcn_mfma_f32_16x16x32_f16(af[mi], wf, acc[cls][mi], 0, 0, 0);
      }
    }
    if (kc < 7){
      char* An = smem + ((kc+1)&1)*16384;
      #pragma unroll
      for (int i = 0; i < 8; ++i){
        int r = (tid>>4) + i*16, bby = (tid & 15)*8;
        int sb = (bby & 8) | ((bby & 0x70) ^ ((r & 7) << 4));
        f16x4 c; c[0]=(_Float16)areg[i].x; c[1]=(_Float16)areg[i].y;
                 c[2]=(_Float16)areg[i].z; c[3]=(_Float16)areg[i].w;
        *(f16x4*)(An + r*128 + sb) = c;
      }
    }
    __syncthreads();
  }

  // epilogue: C/D layout col=lane&15, row=(lane>>4)*4+reg
  const int jloc = wave*16 + (lane & 15);
  const int j = jblk*64 + jloc;
  const float bir = bi[j], biz = bi[512 + j], bin = bi[1024 + j], bh = bhn[j];
  #pragma unroll
  for (int mi = 0; mi < 8; ++mi){
    #pragma unroll
    for (int rg = 0; rg < 4; ++rg){
      int r = mi*16 + (lane >> 4)*4 + rg;
      u32 e = rows[tm*128 + r];
      int tt = (int)(e & 511u), bb = (int)((e >> 9) & 127u);
      float xr = acc[0][mi][rg] + bir;
      float xz = acc[1][mi][rg] + biz;
      float xn = acc[2][mi][rg] + bin;
      if ((e >> 16) == 1u){        // reset row: h = (1-z)*n, hn = 0
        float rr = sigm(xr), zz = sigm(xz);
        float nn = tanh_fast(xn + rr*bh);
        ys[((size_t)(tt*128 + bb))*512 + j] = (1.f - zz)*nn;
      } else {
        u32 xi = (u32)(tm*128 + r) - n0;
        if (xi >= XGCAP) xi = 0;
        _Float16* p = xg + (size_t)xi*1536 + jblk*192 + jloc;
        p[0]   = (_Float16)xr;
        p[64]  = (_Float16)xz;
        p[128] = (_Float16)xn;
      }
    }
  }
  __syncthreads();   // all stores drained (vmcnt0 at barrier) before flag bumps
  if (tid < 128){
    u32 e = rows[tm*128 + tid];
    if ((e >> 16) == 1u){
      u32 fidx = (e & 511u)*128u + ((e >> 9) & 127u);
      __hip_atomic_fetch_add(&flags[fidx], 1u, __ATOMIC_RELAXED, __HIP_MEMORY_SCOPE_AGENT);
    }
  }
}

// ---------------------------------------------------------------------------
// Scan: dataflow, NO fences. ys via agent-scope atomics (coherent at L3),
// flags via agent atomics. W fragments read from global (L2-resident).
// A gathered with register prefetch depth 3 into a 4-buffer LDS ring.
// xg epilogue operands prefetched into registers BEFORE the K-pipeline so
// their L3/HBM latency hides under the MFMA chunks.
// ---------------------------------------------------------------------------
__global__ __launch_bounds__(256, 2) void gru_scan(
    const float* __restrict__ h0, const float* __restrict__ bhn,
    const char* __restrict__ wimg, const _Float16* __restrict__ xg,
    const u32* __restrict__ rows, const u32* __restrict__ off,
    const int* __restrict__ nlists, u32* __restrict__ flags,
    float* __restrict__ out)
{
  __shared__ __align__(16) char smem[32768];  // ring of 4 x 8 KB A-chunk buffers
  float* ys = out + 65536;
  const int L = *nlists;
  const u32 n0 = off[1];
  const int tid = threadIdx.x;
  const int lane = tid & 63, wave = tid >> 6;
  const int nblk = (int)gridDim.x;

  int myNext = (int)blockIdx.x;
  int gt = 0;
  for (int li = 1; li < L; ++li){
    const u32 offA = off[li];
    const int nA = (int)(off[li+1] - offA);
    const int tA = (nA + 63) >> 6;
    const int nt = tA * 8;
    while (myNext < gt + nt){
      const int tile = myNext - gt;
      myNext += nblk;
      const int tm = tile >> 3, jb = tile & 7;
      const u32 rowbase = offA + (u32)tm*64u;
      const int mcount = min(64, nA - tm*64);
      const char* wp = wimg + ((size_t)jb*16 + 8)*24576;
      const int jloc = wave*16 + (lane & 15);

      // ---- wait: wave 0 polls per-row flags; barrier releases the block
      if (wave == 0){
        u32 e = rows[rowbase + lane];
        if (lane < mcount && (e >> 16) == 0u){
          u32 fidx = ((e & 511u) - 1u)*128u + ((e >> 9) & 127u);
          int guard = 0;
          while (__hip_atomic_load(&flags[fidx], __ATOMIC_RELAXED, __HIP_MEMORY_SCOPE_AGENT) < 8u){
            __builtin_amdgcn_s_sleep(1);
            if (++guard > (1 << 20)) break;
          }
        }
      }
      __syncthreads();

      const float* rp[4];
      #pragma unroll
      for (int i = 0; i < 4; ++i){
        u32 e = rows[rowbase + (tid>>4) + i*16];
        int tt = (int)(e & 511u), bb = (int)((e >> 9) & 127u);
        const float* base = ((e >> 16) == 0u) ? (ys + ((size_t)((tt-1)*128 + bb))*512)
                                              : (h0 + (size_t)bb*512);
        rp[i] = base + (tid & 15)*4;
      }

      // ---- xg prefetch: 48 scalar halves per thread, in flight across the
      // whole K-pipeline (xi = list position - n0, no rows[] needed)
      _Float16 xgp[3][4][4];
      #pragma unroll
      for (int mi = 0; mi < 4; ++mi){
        #pragma unroll
        for (int rg = 0; rg < 4; ++rg){
          u32 lpos = rowbase + (u32)(mi*16 + (lane >> 4)*4 + rg);
          u32 xi = lpos - n0;
          if (xi >= XGCAP) xi = 0;
          const _Float16* p = xg + (size_t)xi*1536 + jb*192 + jloc;
          xgp[0][mi][rg] = p[0];
          xgp[1][mi][rg] = p[64];
          xgp[2][mi][rg] = p[128];
        }
      }

      f32x4 acc[3][4];
      #pragma unroll
      for (int c = 0; c < 3; ++c)
        #pragma unroll
        for (int m = 0; m < 4; ++m) acc[c][m] = (f32x4){0.f,0.f,0.f,0.f};
      float hp[4][4];
      double s0[4][2], s1[4][2], s2[4][2];

#define ALOAD(S, CK) do{ \
    _Pragma("unroll") for (int i_ = 0; i_ < 4; ++i_){ \
      const double* p_ = (const double*)(rp[i_] + (CK)*64); \
      S[i_][0] = aload(p_); S[i_][1] = aload(p_ + 1); } }while(0)

#define AWRITE(S, CK) do{ \
    char* An_ = smem + ((CK) & 3)*8192; \
    _Pragma("unroll") for (int i_ = 0; i_ < 4; ++i_){ \
      float2 u0_ = d2f2(S[i_][0]), u1_ = d2f2(S[i_][1]); \
      int r_ = (tid>>4) + i_*16, bby_ = (tid & 15)*8; \
      int sb_ = (bby_ & 8) | ((bby_ & 0x70) ^ ((r_ & 7) << 4)); \
      f16x4 c_; c_[0]=(_Float16)u0_.x; c_[1]=(_Float16)u0_.y; \
                c_[2]=(_Float16)u1_.x; c_[3]=(_Float16)u1_.y; \
      *(f16x4*)(An_ + r_*128 + sb_) = c_; } }while(0)

#define COMPUTE(KC) do{ \
    const char* Ab_ = smem + ((KC) & 3)*8192; \
    _Pragma("unroll") for (int kk_ = 0; kk_ < 2; ++kk_){ \
      const int bby_ = kk_*64 + (lane>>4)*16; \
      f16x8 af_[4]; \
      _Pragma("unroll") for (int mi_ = 0; mi_ < 4; ++mi_){ \
        int rr_ = mi_*16 + (lane & 15); \
        af_[mi_] = *(const f16x8*)(Ab_ + rr_*128 + (bby_ ^ ((rr_ & 7) << 4))); } \
      _Pragma("unroll") for (int cl_ = 0; cl_ < 3; ++cl_){ \
        int cc_ = cl_*64 + wave*16 + (lane & 15); \
        f16x8 wf_ = *(const f16x8*)(wp + (size_t)(KC)*24576 + cc_*128 + (bby_ ^ ((cc_ & 7) << 4))); \
        _Pragma("unroll") for (int mi_ = 0; mi_ < 4; ++mi_) \
          acc[cl_][mi_] = __builtin_amdgcn_mfma_f32_16x16x32_f16(af_[mi_], wf_, acc[cl_][mi_], 0, 0, 0); } } \
    if ((KC) == jb){ \
      const int bb2_ = jloc*2; \
      _Pragma("unroll") for (int mi_ = 0; mi_ < 4; ++mi_) \
        _Pragma("unroll") for (int rg_ = 0; rg_ < 4; ++rg_){ \
          int r2_ = mi_*16 + (lane >> 4)*4 + rg_; \
          int sb2_ = (bb2_ & 0x0F) | ((bb2_ & 0x70) ^ ((r2_ & 7) << 4)); \
          hp[mi_][rg_] = (float)(*(const _Float16*)(Ab_ + r2_*128 + sb2_)); } } }while(0)

      // prologue: 3 chunk-loads in flight, write chunk 0
      ALOAD(s0, 0); ALOAD(s1, 1); ALOAD(s2, 2);
      AWRITE(s0, 0);
      __syncthreads();
      // steady: load k+3 | compute k | write k+1 | barrier
      ALOAD(s0, 3); COMPUTE(0); AWRITE(s1, 1); __syncthreads();
      ALOAD(s1, 4); COMPUTE(1); AWRITE(s2, 2); __syncthreads();
      ALOAD(s2, 5); COMPUTE(2); AWRITE(s0, 3); __syncthreads();
      ALOAD(s0, 6); COMPUTE(3); AWRITE(s1, 4); __syncthreads();
      ALOAD(s1, 7); COMPUTE(4); AWRITE(s2, 5); __syncthreads();
                    COMPUTE(5); AWRITE(s0, 6); __syncthreads();
                    COMPUTE(6); AWRITE(s1, 7); __syncthreads();
                    COMPUTE(7);
#undef ALOAD
#undef AWRITE
#undef COMPUTE

      // epilogue: gates + h_new (agent-scope stores -> visible to consumers)
      const int j = jb*64 + jloc;
      const float bh = bhn[j];
      #pragma unroll
      for (int mi = 0; mi < 4; ++mi){
        #pragma unroll
        for (int rg = 0; rg < 4; ++rg){
          int r = mi*16 + (lane >> 4)*4 + rg;
          if (r < mcount){
            u32 e = rows[rowbase + r];
            int tt = (int)(e & 511u), bb = (int)((e >> 9) & 127u);
            float rr = sigm((float)xgp[0][mi][rg] + acc[0][mi][rg]);
            float zz = sigm((float)xgp[1][mi][rg] + acc[1][mi][rg]);
            float nn = tanh_fast((float)xgp[2][mi][rg] + rr*(acc[2][mi][rg] + bh));
            astore(&ys[((size_t)(tt*128 + bb))*512 + j], (1.f - zz)*nn + zz*hp[mi][rg]);
          }
        }
      }
      __syncthreads();   // vmcnt(0) drained -> stores at coherence point
      if (tid < mcount){
        u32 e = rows[rowbase + tid];
        u32 fidx = (e & 511u)*128u + ((e >> 9) & 127u);
        __hip_atomic_fetch_add(&flags[fidx], 1u, __ATOMIC_RELAXED, __HIP_MEMORY_SCOPE_AGENT);
      }
    }
    gt += nt;
  }

  // h_final = ys[511] -> out[0:65536], gated on t=511 row readiness
  for (int v = (int)blockIdx.x; v < 512; v += nblk){
    const int b = v & 127, jq = v >> 7;
    if (tid == 0){
      int guard = 0;
      while (__hip_atomic_load(&flags[511*128 + b], __ATOMIC_RELAXED, __HIP_MEMORY_SCOPE_AGENT) < 8u){
        __builtin_amdgcn_s_sleep(1);
        if (++guard > (1 << 20)) break;
      }
    }
    __syncthreads();
    if (tid < 128){
      const float* src = &ys[((size_t)(511*128 + b))*512 + jq*128 + tid];
      float val = __hip_atomic_load(src, __ATOMIC_RELAXED, __HIP_MEMORY_SCOPE_AGENT);
      out[(size_t)b*512 + jq*128 + tid] = val;
    }
    __syncthreads();
  }
}

// ---------------------------------------------------------------------------
extern "C" void kernel_launch(void* const* d_in, const int* in_sizes, int n_in,
                              void* d_out, int out_size, void* d_ws, size_t ws_size,
                              hipStream_t stream)
{
  const float* x  = (const float*)d_in[0];
  const void*  resets = d_in[1];
  const float* h0 = (const float*)d_in[2];
  const float* Wi = (const float*)d_in[3];
  const float* bi = (const float*)d_in[4];
  const float* Wh = (const float*)d_in[5];
  const float* bhn= (const float*)d_in[6];
  float* out = (float*)d_out;

  char* ws = (char*)d_ws;
  u32* off    = (u32*)ws;                       // 521 u32
  int* nlists = (int*)(ws + 4096);
  u32* rows   = (u32*)(ws + 8192);              // 65536+64 u32
  u32* flags  = (u32*)(ws + 294912);            // 65536 u32
  char* wimg  = ws + 589824;                    // 8*16*24576 = 3.07 MB
  _Float16* xg = (_Float16*)(ws + 4194304);     // XGCAP*1536 fp16 = 113 MB

  hipMemsetAsync(flags, 0, 65536*sizeof(u32), stream);
  prep_lists<<<dim3(1), dim3(512), 0, stream>>>(resets, rows, off, nlists);
  prep_w<<<dim3(384), dim3(256), 0, stream>>>(Wi, Wh, wimg);
  xg_gemm<<<dim3(4096), dim3(256), 0, stream>>>(x, bi, bhn, wimg, xg, rows, off, flags, out);

  // co-residency guarantee for the spin-wait dataflow
  int perCU = 0;
  (void)hipOccupancyMaxActiveBlocksPerMultiprocessor(&perCU, gru_scan, 256, 0);
  if (perCU < 1) perCU = 1;
  int grid = perCU * 256;
  if (grid > 1024) grid = 1024;

  void* args[] = {(void*)&h0, (void*)&bhn, (void*)&wimg, (void*)&xg,
                  (void*)&rows, (void*)&off, (void*)&nlists, (void*)&flags, (void*)&out};
  hipLaunchCooperativeKernel(gru_scan, dim3(grid), dim3(256), args, 0, stream);

  (void)in_sizes; (void)n_in; (void)out_size; (void)ws_size;
}